// Round 3
// baseline (507.587 us; speedup 1.0000x reference)
//
#include <hip/hip_runtime.h>
#include <math.h>

#define N_CH 17
#define IN_H 64
#define IN_W 32
#define HW 128

// LDS layout (per channel-of-pair):
//   s_in: 68 rows x 32 cols (rows 0,1,66,67 zero pads; data floats [64,2112))
//   tmp : 16 rows x stride 37 (cols 0,1,34,35 zero pads; data at col+2)
#define SIN_CH 2176
#define TMP_STRIDE 37
#define TMP_CH (16 * TMP_STRIDE)   // 592
#define EDGE (32.f / 28.f)

// LDS-visibility barrier that does NOT drain vmcnt: prefetched global loads
// stay in flight across it (m97 lesson: __syncthreads emits vmcnt(0) drain).
#define BAR_LGKM() asm volatile("s_waitcnt lgkmcnt(0)\n\ts_barrier" ::: "memory")

__global__ __launch_bounds__(256, 6)
void heatmap_kernel(const float* __restrict__ x,
                    float* __restrict__ out_heat,   // [N,3,16,8]
                    float* __restrict__ out_mr,     // [N,3]
                    float* __restrict__ out_mi) {   // [N,17,2]
    const int n = blockIdx.x;
    const int t = threadIdx.x;
    const int w = t >> 6, l = t & 63;
    const int half = t >> 7;          // 0: channel A (waves 0,1), 1: B (waves 2,3)
    const int tl = t & 127;
    const int col = tl & 31, q = tl >> 5;   // stage1: this thread owns rows 4q..4q+3
    const int p = tl;                        // stage2 position 0..127
    const int r2 = p >> 3, oc = p & 7;
    const int hpos = w & 1;                  // positions 0-63 vs 64-127

    __shared__ float s_in[2 * SIN_CH];       // 17408 B (overlaid by s_part later)
    __shared__ float s_tmp[2 * TMP_CH];      // 4736 B
    __shared__ float s_cval[N_CH * 2];
    __shared__ int   s_cidx[N_CH * 2];

    float* sw = s_in + half * SIN_CH;
    float* st = s_tmp + half * TMP_CH;

    // zero pad zones once (never overwritten: staging writes floats [64,2112),
    // tmp writes only data cols)
    s_in[half * SIN_CH + (tl < 64 ? tl : 2048 + tl)] = 0.f;
    if (t < 128) {
        int ch = t >> 6, rr = (t >> 2) & 15, jj = t & 3;
        int cc = (jj < 2) ? jj : jj + 32;
        s_tmp[ch * TMP_CH + rr * TMP_STRIDE + cc] = 0.f;
    }

    const float* xn = x + (size_t)n * N_CH * IN_H * IN_W;
    float ga0 = 0.f, ga1 = 0.f, ga2 = 0.f;   // per-position group sums

    float4 bA[4], bB[4];
    {   // preload iter-0 channel (A: c=0, B: c=1); 128 threads x 4 float4, coalesced
        const float4* src = (const float4*)(xn + (size_t)half * (IN_H * IN_W));
#pragma unroll
        for (int j = 0; j < 4; ++j) bA[j] = src[tl + 128 * j];
    }

    auto process = [&](float4 (&cur)[4], float4 (&nxt)[4], int i) {
        const int c = 2 * i + half;
        const bool valid = (c < N_CH);

        // staged regs -> s_in data region
        float4* dst = (float4*)(sw + 64);
#pragma unroll
        for (int j = 0; j < 4; ++j) dst[tl + 128 * j] = cur[j];

        // prefetch next pair (survives the lgkm-only barriers below)
        if (i < 8) {
            int cn = 2 * (i + 1) + half;
            cn = cn > 16 ? 16 : cn;   // clamp: avoids OOB on last batch
            const float4* src = (const float4*)(xn + (size_t)cn * (IN_H * IN_W));
#pragma unroll
            for (int j = 0; j < 4; ++j) nxt[j] = src[tl + 128 * j];
        }

        BAR_LGKM();   // staging visible to all waves; prefetch stays in flight

        // stage 1 (H 64->16): read this thread's 20-row window once
        const float W[8] = {1.f/32.f, 3.f/32.f, 5.f/32.f, 7.f/32.f,
                            7.f/32.f, 5.f/32.f, 3.f/32.f, 1.f/32.f};
        float v[20];
#pragma unroll
        for (int d = 0; d < 20; ++d) v[d] = sw[(16 * q + d) * 32 + col];

        BAR_LGKM();   // all s_in reads done -> next iter may overwrite s_in

        float o4[4];
#pragma unroll
        for (int k = 0; k < 4; ++k) {
            float acc = 0.f;
#pragma unroll
            for (int d = 0; d < 8; ++d) acc += W[d] * v[4 * k + d];
            if ((q == 0 && k == 0) || (q == 3 && k == 3)) acc *= EDGE;
            o4[k] = acc;
        }
#pragma unroll
        for (int k = 0; k < 4; ++k)
            st[(4 * q + k) * TMP_STRIDE + 2 + col] = o4[k];

        asm volatile("" ::: "memory");

        // stage 2 (W 32->8): wave-local (wave reads only tmp rows it wrote)
        float o = 0.f;
#pragma unroll
        for (int d = 0; d < 8; ++d) o += W[d] * st[r2 * TMP_STRIDE + 4 * oc + d];
        if (oc == 0 || oc == 7) o *= EDGE;

        if (valid) {
            if (c < 5)       ga0 += o;
            else if (c < 11) ga1 += o;
            else             ga2 += o;

            // wave-local argmax (first-index tiebreak)
            float bv = o; int bi = p;
#pragma unroll
            for (int off = 32; off >= 1; off >>= 1) {
                float ov = __shfl_down(bv, off);
                int   oi = __shfl_down(bi, off);
                if (ov > bv || (ov == bv && oi < bi)) { bv = ov; bi = oi; }
            }
            if (l == 0) { s_cval[2 * c + hpos] = bv; s_cidx[2 * c + hpos] = bi; }
        }
    };

#pragma unroll
    for (int i = 0; i < 9; ++i) {
        if (i & 1) process(bB, bA, i);
        else       process(bA, bB, i);
    }

    __syncthreads();                 // loop fully done; s_in now dead
    float* s_part = s_in;            // overlay [2][3][128]
    s_part[(half * 3 + 0) * HW + p] = ga0;
    s_part[(half * 3 + 1) * HW + p] = ga1;
    s_part[(half * 3 + 2) * HW + p] = ga2;
    __syncthreads();

    if (w < 3) {
        // wave g: softmax over 128 positions of group g (barrier-free)
        const int g = w;
        float v0 = s_part[g * HW + l]      + s_part[(3 + g) * HW + l];
        float v1 = s_part[g * HW + 64 + l] + s_part[(3 + g) * HW + 64 + l];
        float m = fmaxf(v0, v1);
#pragma unroll
        for (int off = 1; off < 64; off <<= 1) m = fmaxf(m, __shfl_xor(m, off));
        float e0 = expf(v0 - m), e1 = expf(v1 - m);
        float s = e0 + e1;
#pragma unroll
        for (int off = 1; off < 64; off <<= 1) s += __shfl_xor(s, off);
        float inv = 1.f / s;
        float* dsto = out_heat + ((size_t)n * 3 + g) * HW;
        dsto[l]      = e0 * inv;
        dsto[l + 64] = e1 * inv;
    } else {
        // wave 3: combine argmax halves + group means
        if (l < N_CH) {
            int c = l;
            float v0 = s_cval[2 * c], v1 = s_cval[2 * c + 1];
            int i0 = s_cidx[2 * c], i1 = s_cidx[2 * c + 1];
            int bi = (v1 > v0) ? i1 : i0;     // tie -> half 0 (lower index)
            float* mi = out_mi + ((size_t)n * N_CH + c) * 2;
            mi[0] = (float)(bi & 7);
            mi[1] = (float)(bi >> 3);
        }
        if (l < 3) {
            int lo = (l == 0) ? 0 : ((l == 1) ? 5 : 11);
            int hi = (l == 0) ? 5 : ((l == 1) ? 11 : 17);
            float acc = 0.f;
            for (int c2 = lo; c2 < hi; ++c2)
                acc += fmaxf(s_cval[2 * c2], s_cval[2 * c2 + 1]);
            out_mr[(size_t)n * 3 + l] = acc / (float)(hi - lo);
        }
    }
}

extern "C" void kernel_launch(void* const* d_in, const int* in_sizes, int n_in,
                              void* d_out, int out_size, void* d_ws, size_t ws_size,
                              hipStream_t stream) {
    const float* x = (const float*)d_in[0];
    float* out = (float*)d_out;
    const int N = in_sizes[0] / (N_CH * IN_H * IN_W);  // 2048
    float* out_heat = out;                             // N*3*128
    float* out_mr   = out_heat + (size_t)N * 3 * HW;   // N*3
    float* out_mi   = out_mr + (size_t)N * 3;          // N*17*2
    heatmap_kernel<<<dim3(N), dim3(256), 0, stream>>>(x, out_heat, out_mr, out_mi);
}

// Round 4
// 379.324 us; speedup vs baseline: 1.3381x; 1.3381x over previous
//
#include <hip/hip_runtime.h>
#include <math.h>

#define N_CH 17
#define IN_H 64
#define IN_W 32
#define HW 128

// LDS layout (per channel-half):
//   s_in: 68 rows x 32 cols (rows 0,1,66,67 zero pads; data floats [64,2112))
//   tmp : 16 rows x stride 37 (cols 0,1,34,35 zero pads; data at col+2)
#define SIN_CH 2176
#define TMP_STRIDE 37
#define TMP_CH (16 * TMP_STRIDE)   // 592
#define EDGE (32.f / 28.f)

// LDS-visibility barrier that does NOT drain vmcnt: prefetched global loads
// stay in flight across it (m97 lesson: __syncthreads emits vmcnt(0) drain).
#define BAR_LGKM() asm volatile("s_waitcnt lgkmcnt(0)\n\ts_barrier" ::: "memory")

#define W0 (1.f/32.f)
#define W1 (3.f/32.f)
#define W2 (5.f/32.f)
#define W3 (7.f/32.f)

// 8-tap on padded rows starting at relative row R (stride 32 floats)
#define TAP8(b, R) (W0*(b)[(R)*32]     + W1*(b)[((R)+1)*32] + W2*(b)[((R)+2)*32] \
                  + W3*(b)[((R)+3)*32] + W3*(b)[((R)+4)*32] + W2*(b)[((R)+5)*32] \
                  + W1*(b)[((R)+6)*32] + W0*(b)[((R)+7)*32])

__global__ __launch_bounds__(256)
void heatmap_kernel(const float* __restrict__ x,
                    float* __restrict__ out_heat,   // [N,3,16,8]
                    float* __restrict__ out_mr,     // [N,3]
                    float* __restrict__ out_mi) {   // [N,17,2]
    const int n = blockIdx.x;
    const int t = threadIdx.x;
    const int w = t >> 6, l = t & 63;
    const int half = t >> 7;          // 0: channels even (waves 0,1), 1: odd (2,3)
    const int tl = t & 127;
    const int col = tl & 31, q = tl >> 5;   // stage1: owns output rows 4q..4q+3
    const int p = tl;                        // stage2 position 0..127
    const int r2 = p >> 3, oc = p & 7;
    const int hpos = w & 1;                  // positions 0-63 vs 64-127

    __shared__ float s_in[2 * SIN_CH];       // 17408 B (overlaid by s_part later)
    __shared__ float s_tmp[2 * TMP_CH];      // 4736 B
    __shared__ float s_cval[N_CH * 2];
    __shared__ int   s_cidx[N_CH * 2];

    float* sw = s_in + half * SIN_CH;
    float* st = s_tmp + half * TMP_CH;

    // zero pad zones once (staging writes only floats [64,2112); tmp writes
    // only data cols) — visible to all waves after iter-0's first barrier
    s_in[half * SIN_CH + (tl < 64 ? tl : 2048 + tl)] = 0.f;
    if (t < 128) {
        int ch = t >> 6, rr = (t >> 2) & 15, jj = t & 3;
        int cc = (jj < 2) ? jj : jj + 32;
        s_tmp[ch * TMP_CH + rr * TMP_STRIDE + cc] = 0.f;
    }

    const float* xn = x + (size_t)n * N_CH * IN_H * IN_W;
    float ga0 = 0.f, ga1 = 0.f, ga2 = 0.f;   // per-position group sums

    // explicit ping-pong buffers — NO arrays, NO lambda (R3 spilled to scratch:
    // VGPR=36, WRITE_SIZE 413MB). Ternary selects resolve statically under unroll.
    float4 A0, A1, A2, A3, B0, B1, B2, B3;
    {   // preload iter-0 channel (c = half); 128 threads x 4 float4, coalesced
        const float4* src = (const float4*)(xn + (size_t)half * (IN_H * IN_W));
        A0 = src[tl]; A1 = src[tl + 128]; A2 = src[tl + 256]; A3 = src[tl + 384];
    }

#pragma unroll
    for (int i = 0; i < 9; ++i) {
        const int c = 2 * i + half;
        const bool valid = (c < N_CH);

        // prefetch next pair first (loads stay in flight across lgkm barriers)
        if (i < 8) {
            int cn = 2 * (i + 1) + half;
            if (cn > 16) cn = 16;   // clamp keeps address in-bounds (result unused)
            const float4* src = (const float4*)(xn + (size_t)cn * (IN_H * IN_W));
            if (i & 1) { A0 = src[tl]; A1 = src[tl+128]; A2 = src[tl+256]; A3 = src[tl+384]; }
            else       { B0 = src[tl]; B1 = src[tl+128]; B2 = src[tl+256]; B3 = src[tl+384]; }
        }

        // stage current regs -> s_in data region
        {
            float4* dst = (float4*)(sw + 64);
            dst[tl]       = (i & 1) ? B0 : A0;
            dst[tl + 128] = (i & 1) ? B1 : A1;
            dst[tl + 256] = (i & 1) ? B2 : A2;
            dst[tl + 384] = (i & 1) ? B3 : A3;
        }

        BAR_LGKM();   // staging visible to all waves; prefetch still in flight

        // stage 1 (H 64->16): 4 output rows, direct LDS taps (CSE handles overlap)
        const float* b = sw + (16 * q) * 32 + col;
        float o0 = TAP8(b, 0);
        float o1 = TAP8(b, 4);
        float o2 = TAP8(b, 8);
        float o3 = TAP8(b, 12);
        if (q == 0) o0 *= EDGE;
        if (q == 3) o3 *= EDGE;

        BAR_LGKM();   // all s_in reads consumed -> next iter may overwrite s_in

        st[(4 * q + 0) * TMP_STRIDE + 2 + col] = o0;
        st[(4 * q + 1) * TMP_STRIDE + 2 + col] = o1;
        st[(4 * q + 2) * TMP_STRIDE + 2 + col] = o2;
        st[(4 * q + 3) * TMP_STRIDE + 2 + col] = o3;

        // stage 2 (W 32->8): wave-local (this wave wrote exactly rows r2 covers)
        const float* b2 = st + r2 * TMP_STRIDE + 4 * oc;
        float o = W0*b2[0] + W1*b2[1] + W2*b2[2] + W3*b2[3]
                + W3*b2[4] + W2*b2[5] + W1*b2[6] + W0*b2[7];
        if (oc == 0 || oc == 7) o *= EDGE;

        if (valid) {
            if (c < 5)       ga0 += o;
            else if (c < 11) ga1 += o;
            else             ga2 += o;

            // wave-local argmax over this wave's 64 positions (first-index tie)
            float bv = o; int bi = p;
#pragma unroll
            for (int off = 32; off >= 1; off >>= 1) {
                float ov = __shfl_down(bv, off);
                int   oi = __shfl_down(bi, off);
                if (ov > bv || (ov == bv && oi < bi)) { bv = ov; bi = oi; }
            }
            if (l == 0) { s_cval[2 * c + hpos] = bv; s_cidx[2 * c + hpos] = bi; }
        }
    }

    __syncthreads();                 // loop fully done; s_in now dead
    float* s_part = s_in;            // overlay [2][3][128]
    s_part[(half * 3 + 0) * HW + p] = ga0;
    s_part[(half * 3 + 1) * HW + p] = ga1;
    s_part[(half * 3 + 2) * HW + p] = ga2;
    __syncthreads();

    if (w < 3) {
        // wave g: softmax over 128 positions of group g (barrier-free)
        const int g = w;
        float v0 = s_part[g * HW + l]      + s_part[(3 + g) * HW + l];
        float v1 = s_part[g * HW + 64 + l] + s_part[(3 + g) * HW + 64 + l];
        float m = fmaxf(v0, v1);
#pragma unroll
        for (int off = 1; off < 64; off <<= 1) m = fmaxf(m, __shfl_xor(m, off));
        float e0 = expf(v0 - m), e1 = expf(v1 - m);
        float s = e0 + e1;
#pragma unroll
        for (int off = 1; off < 64; off <<= 1) s += __shfl_xor(s, off);
        float inv = 1.f / s;
        float* dsto = out_heat + ((size_t)n * 3 + g) * HW;
        dsto[l]      = e0 * inv;
        dsto[l + 64] = e1 * inv;
    } else {
        // wave 3: combine argmax halves + group means
        if (l < N_CH) {
            int c = l;
            float v0 = s_cval[2 * c], v1 = s_cval[2 * c + 1];
            int i0 = s_cidx[2 * c], i1 = s_cidx[2 * c + 1];
            int bi = (v1 > v0) ? i1 : i0;     // tie -> lower-index half
            float* mi = out_mi + ((size_t)n * N_CH + c) * 2;
            mi[0] = (float)(bi & 7);
            mi[1] = (float)(bi >> 3);
        }
        if (l < 3) {
            int lo = (l == 0) ? 0 : ((l == 1) ? 5 : 11);
            int hi = (l == 0) ? 5 : ((l == 1) ? 11 : 17);
            float acc = 0.f;
            for (int c2 = lo; c2 < hi; ++c2)
                acc += fmaxf(s_cval[2 * c2], s_cval[2 * c2 + 1]);
            out_mr[(size_t)n * 3 + l] = acc / (float)(hi - lo);
        }
    }
}

extern "C" void kernel_launch(void* const* d_in, const int* in_sizes, int n_in,
                              void* d_out, int out_size, void* d_ws, size_t ws_size,
                              hipStream_t stream) {
    const float* x = (const float*)d_in[0];
    float* out = (float*)d_out;
    const int N = in_sizes[0] / (N_CH * IN_H * IN_W);  // 2048
    float* out_heat = out;                             // N*3*128
    float* out_mr   = out_heat + (size_t)N * 3 * HW;   // N*3
    float* out_mi   = out_mr + (size_t)N * 3;          // N*17*2
    heatmap_kernel<<<dim3(N), dim3(256), 0, stream>>>(x, out_heat, out_mr, out_mi);
}